// Round 1
// 382.481 us; speedup vs baseline: 1.0468x; 1.0468x over previous
//
#include <hip/hip_runtime.h>
#include <hip/hip_fp16.h>

#define NV 50000
#define EV 800000
#define INF 128
#define HD 64
#define KNEG 5
#define NB ((NV + 1023) / 1024)   // 49 scan blocks

// ------- embed + hist fused, v2: W-in-VGPR, wave-private dbuf ---------
// h = feat @ W + b  (50000 x 128 @ 128 x 64), then degree histogram.
// Each wave owns groups of 4 nodes (512 contiguous floats of feat).
// Lane f holds column W[:,f] in 128 VGPRs -> zero weight reads in loop.
// Feat rows staged via wave-private LDS double buffer (no barriers).
__global__ __launch_bounds__(256) void embed_hist_kernel(
    const float* __restrict__ feat, const float* __restrict__ W,
    const float* __restrict__ b, float* __restrict__ h,
    const int* __restrict__ dst, int* __restrict__ deg) {
  __shared__ float sF[4][2][512];   // wave x buf x (4 rows * 128) = 16 KB
  const int lane = threadIdx.x & 63;
  const int wave = threadIdx.x >> 6;
  // column f of W into registers (static-index, fully unrolled)
  float Wreg[INF];
#pragma unroll
  for (int k = 0; k < INF; k++) Wreg[k] = W[k * HD + lane];
  const float bias = b[lane];
  const int nwaves = gridDim.x * 4;
  const int wid = blockIdx.x * 4 + wave;   // wave-uniform
  const int ngroups = NV / 4;              // 12500 exactly (NV % 4 == 0)

  int buf = 0;
  int g = wid;
  if (g < ngroups) {
    const float4* gp = (const float4*)(feat + (size_t)g * 512);
    const float4 a0 = gp[lane];
    const float4 a1 = gp[lane + 64];
    ((float4*)sF[wave][0])[lane] = a0;
    ((float4*)sF[wave][0])[lane + 64] = a1;
  }
  for (; g < ngroups; g += nwaves) {
    const int gn = g + nwaves;
    float4 b0, b1;
    if (gn < ngroups) {                    // wave-uniform guard
      const float4* gp = (const float4*)(feat + (size_t)gn * 512);
      b0 = gp[lane];                       // prefetch next group
      b1 = gp[lane + 64];
    }
    float acc0 = bias, acc1 = bias, acc2 = bias, acc3 = bias;
    const float4* F = (const float4*)sF[wave][buf];
#pragma unroll
    for (int k4 = 0; k4 < 32; k4++) {
      const float4 x0 = F[k4];            // broadcast reads (uniform addr)
      const float4 x1 = F[k4 + 32];
      const float4 x2 = F[k4 + 64];
      const float4 x3 = F[k4 + 96];
      const float w0 = Wreg[4 * k4 + 0];
      const float w1 = Wreg[4 * k4 + 1];
      const float w2 = Wreg[4 * k4 + 2];
      const float w3 = Wreg[4 * k4 + 3];
      acc0 = fmaf(x0.x, w0, acc0); acc0 = fmaf(x0.y, w1, acc0);
      acc0 = fmaf(x0.z, w2, acc0); acc0 = fmaf(x0.w, w3, acc0);
      acc1 = fmaf(x1.x, w0, acc1); acc1 = fmaf(x1.y, w1, acc1);
      acc1 = fmaf(x1.z, w2, acc1); acc1 = fmaf(x1.w, w3, acc1);
      acc2 = fmaf(x2.x, w0, acc2); acc2 = fmaf(x2.y, w1, acc2);
      acc2 = fmaf(x2.z, w2, acc2); acc2 = fmaf(x2.w, w3, acc2);
      acc3 = fmaf(x3.x, w0, acc3); acc3 = fmaf(x3.y, w1, acc3);
      acc3 = fmaf(x3.z, w2, acc3); acc3 = fmaf(x3.w, w3, acc3);
    }
    float* hp = h + (size_t)g * 256 + lane;   // 4 coalesced row stores
    hp[0] = acc0;
    hp[64] = acc1;
    hp[128] = acc2;
    hp[192] = acc3;
    if (gn < ngroups) {                    // write next buf (same-wave DS order)
      ((float4*)sF[wave][buf ^ 1])[lane] = b0;
      ((float4*)sF[wave][buf ^ 1])[lane + 64] = b1;
      buf ^= 1;
    }
  }
  // hist tail: grid-stride over edges
  for (int e = blockIdx.x * 256 + threadIdx.x; e < EV; e += gridDim.x * 256)
    atomicAdd(&deg[dst[e]], 1);
}

// ------- parallel scan, pass 1: per-block exclusive partials ----------
__global__ __launch_bounds__(1024) void scan_part_kernel(
    const int* __restrict__ deg, int* __restrict__ off,
    int* __restrict__ bsum) {
  __shared__ int wsum[16];
  const int tid = threadIdx.x;
  const int lane = tid & 63;
  const int w = tid >> 6;
  const int i = blockIdx.x * 1024 + tid;     // coalesced
  const int v = (i < NV) ? deg[i] : 0;
  int s = v;                                 // wave-inclusive scan
#pragma unroll
  for (int ofs = 1; ofs < 64; ofs <<= 1) {
    int x = __shfl_up(s, ofs, 64);
    if (lane >= ofs) s += x;
  }
  if (lane == 63) wsum[w] = s;
  __syncthreads();
  if (w == 0) {
    int t2 = (lane < 16) ? wsum[lane] : 0;
#pragma unroll
    for (int ofs = 1; ofs < 16; ofs <<= 1) {
      int x = __shfl_up(t2, ofs, 64);
      if (lane >= ofs) t2 += x;
    }
    if (lane < 16) wsum[lane] = t2;
  }
  __syncthreads();
  const int base = (w > 0) ? wsum[w - 1] : 0;
  if (i < NV) off[i] = base + s - v;         // block-local exclusive
  if (tid == 0) bsum[blockIdx.x] = wsum[15]; // block total
}

// ------- parallel scan, pass 2: add block bases; write cursor ---------
__global__ __launch_bounds__(1024) void scan_fix_kernel(
    const int* __restrict__ bsum, int* __restrict__ off,
    int* __restrict__ cursor) {
  __shared__ int sbase, stot;
  const int tid = threadIdx.x;
  const int b = blockIdx.x;
  if (tid == 0) {
    int acc = 0, tot = 0;
    for (int j = 0; j < NB; j++) {           // 49 values — trivial
      const int x = bsum[j];
      if (j < b) acc += x;
      tot += x;
    }
    sbase = acc;
    stot = tot;
  }
  __syncthreads();
  const int i = b * 1024 + tid;              // coalesced
  if (i < NV) {
    const int o = off[i] + sbase;
    off[i] = o;
    cursor[i] = o;
  }
  if (b == NB - 1 && tid == 0) off[NV] = stot;   // == EV
}

// ------- CSR perm: gsrc[pos] = src[e], grouped by dst -----------------
__global__ __launch_bounds__(256) void perm_kernel(
    const int* __restrict__ src, const int* __restrict__ dst,
    int* __restrict__ cursor, int* __restrict__ gsrc) {
  const int e = blockIdx.x * 256 + threadIdx.x;
  if (e < EV) {
    const int pos = atomicAdd(&cursor[dst[e]], 1);
    gsrc[pos] = src[e];
  }
}

// ------- fused aggregate + combine (r9-verified version) --------------
__global__ __launch_bounds__(256) void aggcomb_kernel(
    const float* __restrict__ hin, float* __restrict__ hout,
    const int* __restrict__ gsrc, const int* __restrict__ off,
    const float* __restrict__ wconv, const float* __restrict__ cb,
    const float* __restrict__ gamma, const float* __restrict__ beta,
    const float* __restrict__ mean, const float* __restrict__ var) {
  __shared__ float sWs[HD * HD];    // 16 KB
  __shared__ float sWd[HD * HD];    // 16 KB
  __shared__ float sRow[4][2 * HD]; // per-wave: s1 row | h row (2 KB)
  for (int i = threadIdx.x; i < HD * HD / 4; i += 256) {
    ((float4*)sWs)[i] = ((const float4*)wconv)[i];
    ((float4*)sWd)[i] = ((const float4*)(wconv + HD * HD))[i];
  }
  const int wave = threadIdx.x >> 6;
  const int lane = threadIdx.x & 63;
  const int sub = lane >> 4;   // edge slot 0..3
  const int q = lane & 15;     // float4 slot within row
  const int f = lane;          // output feature in phase 2
  const float cbf = cb[f];
  const float gf = gamma[f];
  const float btf = beta[f];
  const float mf = mean[f];
  const float inv = rsqrtf(var[f] + 1e-3f);
  __syncthreads();             // weights staged (only barrier)
  const float4* hp = (const float4*)hin;
  for (int n = blockIdx.x * 4 + wave; n < NV; n += gridDim.x * 4) {
    const int j0 = off[n], j1 = off[n + 1];
    const int deg = j1 - j0;
    const float hv = hin[(size_t)n * HD + lane];  // own h row element
    float4 acc0 = make_float4(0.f, 0.f, 0.f, 0.f);
    float4 acc1 = make_float4(0.f, 0.f, 0.f, 0.f);
    for (int base = 0; base < deg; base += 64) {
      const int cnt = min(64, deg - base);        // wave-uniform
      const int my = (lane < cnt) ? gsrc[j0 + base + lane] : 0;
      int k = 0;
      for (; k + 8 <= cnt; k += 8) {              // uniform: full exec
        const int a0 = __shfl(my, k + sub, 64);
        const int a1 = __shfl(my, k + 4 + sub, 64);
        const float4 v0 = hp[(size_t)a0 * 16 + q];
        const float4 v1 = hp[(size_t)a1 * 16 + q];
        acc0.x += v0.x; acc0.y += v0.y; acc0.z += v0.z; acc0.w += v0.w;
        acc1.x += v1.x; acc1.y += v1.y; acc1.z += v1.z; acc1.w += v1.w;
      }
      for (; k + 4 <= cnt; k += 4) {              // uniform: full exec
        const int a0 = __shfl(my, k + sub, 64);
        const float4 v0 = hp[(size_t)a0 * 16 + q];
        acc0.x += v0.x; acc0.y += v0.y; acc0.z += v0.z; acc0.w += v0.w;
      }
      {
        // tail: shfl hoisted out of the divergent guard (clamped index)
        const int idx = k + sub;
        const int a0 = __shfl(my, (idx < cnt) ? idx : 0, 64);
        if (idx < cnt) {
          const float4 v0 = hp[(size_t)a0 * 16 + q];
          acc1.x += v0.x; acc1.y += v0.y; acc1.z += v0.z; acc1.w += v0.w;
        }
      }
    }
    acc0.x += acc1.x; acc0.y += acc1.y; acc0.z += acc1.z; acc0.w += acc1.w;
#pragma unroll
    for (int m = 16; m <= 32; m <<= 1) {
      acc0.x += __shfl_xor(acc0.x, m, 64);
      acc0.y += __shfl_xor(acc0.y, m, 64);
      acc0.z += __shfl_xor(acc0.z, m, 64);
      acc0.w += __shfl_xor(acc0.w, m, 64);
    }
    // hand-off: wave-private LDS row (in-order DS pipe; no barrier)
    if (sub == 0) ((float4*)&sRow[wave][0])[q] = acc0;  // s1 row
    sRow[wave][HD + lane] = hv;                          // h row
    float a1 = 0.f, a2 = 0.f;
#pragma unroll 8
    for (int k = 0; k < HD; k++) {
      a1 += sRow[wave][k] * sWs[k * HD + f];
      a2 += sRow[wave][HD + k] * sWd[k * HD + f];
    }
    const float d = (float)deg;
    const float agg = a1 + d * a2 + d * cbf;
    const float sig = 1.f / (1.f + __expf(-agg));
    const float sp = fmaxf(hv, 0.f) + log1pf(__expf(-fabsf(hv)));
    float x = sig + sp;
    x = gf * (x - mf) * inv + btf;
    hout[(size_t)n * HD + f] = fmaxf(x, 0.f);
  }
}

// ------- convert h (fp32) -> hh (fp16, RNE) ---------------------------
__global__ __launch_bounds__(256) void convert_kernel(
    const float* __restrict__ h, __half* __restrict__ hh) {
  const int i = blockIdx.x * 256 + threadIdx.x;   // one float4 each
  const int idx = i * 4;
  if (idx < NV * HD) {
    const float4 v = *(const float4*)(h + idx);
    __half2* o = (__half2*)(hh + idx);
    o[0] = __floats2half2_rn(v.x, v.y);
    o[1] = __floats2half2_rn(v.z, v.w);
  }
}

// ------- scores: 8 lanes/edge, fp16 rows (128 B each) -----------------
__global__ __launch_bounds__(256) void score_kernel(
    const __half* __restrict__ hh, const int* __restrict__ src,
    const int* __restrict__ dst, const int* __restrict__ neg_dst,
    const float* __restrict__ wrel, float* __restrict__ out) {
  const int tid = blockIdx.x * 256 + threadIdx.x;
  const int e = tid >> 3;       // 8 edges per wave
  const int q = tid & 7;        // owns features 8q..8q+7 (16 B fp16)
  if (e >= EV) return;
  const float4 w0 = ((const float4*)wrel)[2 * q];
  const float4 w1 = ((const float4*)wrel)[2 * q + 1];
  const int s = src[e];
  const int d = dst[e];
  int nd[KNEG];
#pragma unroll
  for (int r = 0; r < KNEG; r++) nd[r] = neg_dst[e * KNEG + r];

  const uint4* hp = (const uint4*)hh;   // 8 fp16 per uint4, 8 per row
  const uint4 sv = hp[(size_t)s * 8 + q];
  const uint4 dv = hp[(size_t)d * 8 + q];
  uint4 nv[KNEG];
#pragma unroll
  for (int r = 0; r < KNEG; r++) nv[r] = hp[(size_t)nd[r] * 8 + q];

#define FLO(u) __half2float(__low2half(*(const __half2*)&(u)))
#define FHI(u) __half2float(__high2half(*(const __half2*)&(u)))
  // src row * w, fp32
  const float a0 = FLO(sv.x) * w0.x, a1 = FHI(sv.x) * w0.y;
  const float a2 = FLO(sv.y) * w0.z, a3 = FHI(sv.y) * w0.w;
  const float a4 = FLO(sv.z) * w1.x, a5 = FHI(sv.z) * w1.y;
  const float a6 = FLO(sv.w) * w1.z, a7 = FHI(sv.w) * w1.w;

  float p = a0 * FLO(dv.x) + a1 * FHI(dv.x) + a2 * FLO(dv.y) + a3 * FHI(dv.y)
          + a4 * FLO(dv.z) + a5 * FHI(dv.z) + a6 * FLO(dv.w) + a7 * FHI(dv.w);
#pragma unroll
  for (int m = 4; m; m >>= 1) p += __shfl_xor(p, m, 64);
  if (q == 0) out[e] = p;

#pragma unroll
  for (int r = 0; r < KNEG; r++) {
    const uint4 v = nv[r];
    float pn = a0 * FLO(v.x) + a1 * FHI(v.x) + a2 * FLO(v.y) + a3 * FHI(v.y)
             + a4 * FLO(v.z) + a5 * FHI(v.z) + a6 * FLO(v.w) + a7 * FHI(v.w);
#pragma unroll
    for (int m = 4; m; m >>= 1) pn += __shfl_xor(pn, m, 64);
    if (q == 0) out[(size_t)EV + (size_t)e * KNEG + r] = pn;
  }
#undef FLO
#undef FHI
}

extern "C" void kernel_launch(void* const* d_in, const int* in_sizes, int n_in,
                              void* d_out, int out_size, void* d_ws, size_t ws_size,
                              hipStream_t stream) {
  const float* node_feat = (const float*)d_in[0];   // N x 128
  const float* emb_w     = (const float*)d_in[1];   // 128 x 64
  const float* emb_b     = (const float*)d_in[2];   // 64
  const float* conv_w    = (const float*)d_in[3];   // L x 128 x 64
  const float* conv_b    = (const float*)d_in[4];   // L x 64
  const float* bn_gamma  = (const float*)d_in[5];   // L x 64
  const float* bn_beta   = (const float*)d_in[6];
  const float* bn_mean   = (const float*)d_in[7];
  const float* bn_var    = (const float*)d_in[8];
  const float* w_rel     = (const float*)d_in[9];   // 64
  const int*   src       = (const int*)d_in[10];    // E
  const int*   dst       = (const int*)d_in[11];    // E
  const int*   neg_dst   = (const int*)d_in[12];    // E*K
  float* out = (float*)d_out;                       // E + E*K

  // ws layout: h | h2 | off (N+1) | gsrc (E) | bsum (NB)
  // deg/cursor alias h2 (dead before aggcomb writes h2); hh (fp16 h)
  // also aliases h2 (dead after layer-1 aggcomb reads it).
  float* h   = (float*)d_ws;
  float* h2  = h + (size_t)NV * HD;
  int*   off = (int*)(h2 + (size_t)NV * HD);
  int*   gsrc = off + (NV + 1);
  int*   bsum = gsrc + EV;
  int*   deg = (int*)h2;           // alias: h2[0 .. NV)
  int*   cursor = ((int*)h2) + NV; // alias: h2[NV .. 2NV)
  __half* hh = (__half*)h2;        // alias: 6.4 MB of h2

  hipMemsetAsync(deg, 0, (size_t)NV * sizeof(int), stream);
  embed_hist_kernel<<<512, 256, 0, stream>>>(node_feat, emb_w, emb_b, h,
                                             dst, deg);
  scan_part_kernel<<<NB, 1024, 0, stream>>>(deg, off, bsum);
  scan_fix_kernel<<<NB, 1024, 0, stream>>>(bsum, off, cursor);
  perm_kernel<<<(EV + 255) / 256, 256, 0, stream>>>(src, dst, cursor, gsrc);

  // layer 0: h -> h2 ; layer 1: h2 -> h  (ping-pong)
  aggcomb_kernel<<<1024, 256, 0, stream>>>(
      h, h2, gsrc, off, conv_w, conv_b,
      bn_gamma, bn_beta, bn_mean, bn_var);
  aggcomb_kernel<<<1024, 256, 0, stream>>>(
      h2, h, gsrc, off, conv_w + 2 * HD * HD, conv_b + HD,
      bn_gamma + HD, bn_beta + HD, bn_mean + HD, bn_var + HD);

  convert_kernel<<<NV * HD / 4 / 256, 256, 0, stream>>>(h, hh);
  score_kernel<<<((size_t)EV * 8 + 255) / 256, 256, 0, stream>>>(
      hh, src, dst, neg_dst, w_rel, out);
}

// Round 2
// 356.013 us; speedup vs baseline: 1.1247x; 1.0743x over previous
//
#include <hip/hip_runtime.h>
#include <hip/hip_fp16.h>

#define NV 50000
#define EV 800000
#define INF 128
#define HD 64
#define KNEG 5
#define NB ((NV + 1023) / 1024)   // 49 scan blocks

// ------- embed + hist fused, v2: W-in-VGPR, wave-private dbuf ---------
__global__ __launch_bounds__(256) void embed_hist_kernel(
    const float* __restrict__ feat, const float* __restrict__ W,
    const float* __restrict__ b, float* __restrict__ h,
    const int* __restrict__ dst, int* __restrict__ deg) {
  __shared__ float sF[4][2][512];   // wave x buf x (4 rows * 128) = 16 KB
  const int lane = threadIdx.x & 63;
  const int wave = threadIdx.x >> 6;
  float Wreg[INF];
#pragma unroll
  for (int k = 0; k < INF; k++) Wreg[k] = W[k * HD + lane];
  const float bias = b[lane];
  const int nwaves = gridDim.x * 4;
  const int wid = blockIdx.x * 4 + wave;   // wave-uniform
  const int ngroups = NV / 4;              // 12500 exactly

  int buf = 0;
  int g = wid;
  if (g < ngroups) {
    const float4* gp = (const float4*)(feat + (size_t)g * 512);
    const float4 a0 = gp[lane];
    const float4 a1 = gp[lane + 64];
    ((float4*)sF[wave][0])[lane] = a0;
    ((float4*)sF[wave][0])[lane + 64] = a1;
  }
  for (; g < ngroups; g += nwaves) {
    const int gn = g + nwaves;
    float4 b0, b1;
    if (gn < ngroups) {                    // wave-uniform guard
      const float4* gp = (const float4*)(feat + (size_t)gn * 512);
      b0 = gp[lane];
      b1 = gp[lane + 64];
    }
    float acc0 = bias, acc1 = bias, acc2 = bias, acc3 = bias;
    const float4* F = (const float4*)sF[wave][buf];
#pragma unroll
    for (int k4 = 0; k4 < 32; k4++) {
      const float4 x0 = F[k4];
      const float4 x1 = F[k4 + 32];
      const float4 x2 = F[k4 + 64];
      const float4 x3 = F[k4 + 96];
      const float w0 = Wreg[4 * k4 + 0];
      const float w1 = Wreg[4 * k4 + 1];
      const float w2 = Wreg[4 * k4 + 2];
      const float w3 = Wreg[4 * k4 + 3];
      acc0 = fmaf(x0.x, w0, acc0); acc0 = fmaf(x0.y, w1, acc0);
      acc0 = fmaf(x0.z, w2, acc0); acc0 = fmaf(x0.w, w3, acc0);
      acc1 = fmaf(x1.x, w0, acc1); acc1 = fmaf(x1.y, w1, acc1);
      acc1 = fmaf(x1.z, w2, acc1); acc1 = fmaf(x1.w, w3, acc1);
      acc2 = fmaf(x2.x, w0, acc2); acc2 = fmaf(x2.y, w1, acc2);
      acc2 = fmaf(x2.z, w2, acc2); acc2 = fmaf(x2.w, w3, acc2);
      acc3 = fmaf(x3.x, w0, acc3); acc3 = fmaf(x3.y, w1, acc3);
      acc3 = fmaf(x3.z, w2, acc3); acc3 = fmaf(x3.w, w3, acc3);
    }
    float* hpo = h + (size_t)g * 256 + lane;
    hpo[0] = acc0;
    hpo[64] = acc1;
    hpo[128] = acc2;
    hpo[192] = acc3;
    if (gn < ngroups) {
      ((float4*)sF[wave][buf ^ 1])[lane] = b0;
      ((float4*)sF[wave][buf ^ 1])[lane + 64] = b1;
      buf ^= 1;
    }
  }
  for (int e = blockIdx.x * 256 + threadIdx.x; e < EV; e += gridDim.x * 256)
    atomicAdd(&deg[dst[e]], 1);
}

// ------- parallel scan, pass 1 ----------------------------------------
__global__ __launch_bounds__(1024) void scan_part_kernel(
    const int* __restrict__ deg, int* __restrict__ off,
    int* __restrict__ bsum) {
  __shared__ int wsum[16];
  const int tid = threadIdx.x;
  const int lane = tid & 63;
  const int w = tid >> 6;
  const int i = blockIdx.x * 1024 + tid;
  const int v = (i < NV) ? deg[i] : 0;
  int s = v;
#pragma unroll
  for (int ofs = 1; ofs < 64; ofs <<= 1) {
    int x = __shfl_up(s, ofs, 64);
    if (lane >= ofs) s += x;
  }
  if (lane == 63) wsum[w] = s;
  __syncthreads();
  if (w == 0) {
    int t2 = (lane < 16) ? wsum[lane] : 0;
#pragma unroll
    for (int ofs = 1; ofs < 16; ofs <<= 1) {
      int x = __shfl_up(t2, ofs, 64);
      if (lane >= ofs) t2 += x;
    }
    if (lane < 16) wsum[lane] = t2;
  }
  __syncthreads();
  const int base = (w > 0) ? wsum[w - 1] : 0;
  if (i < NV) off[i] = base + s - v;
  if (tid == 0) bsum[blockIdx.x] = wsum[15];
}

// ------- parallel scan, pass 2 ----------------------------------------
__global__ __launch_bounds__(1024) void scan_fix_kernel(
    const int* __restrict__ bsum, int* __restrict__ off,
    int* __restrict__ cursor) {
  __shared__ int sbase, stot;
  const int tid = threadIdx.x;
  const int b = blockIdx.x;
  if (tid == 0) {
    int acc = 0, tot = 0;
    for (int j = 0; j < NB; j++) {
      const int x = bsum[j];
      if (j < b) acc += x;
      tot += x;
    }
    sbase = acc;
    stot = tot;
  }
  __syncthreads();
  const int i = b * 1024 + tid;
  if (i < NV) {
    const int o = off[i] + sbase;
    off[i] = o;
    cursor[i] = o;
  }
  if (b == NB - 1 && tid == 0) off[NV] = stot;
}

// ------- CSR perm -----------------------------------------------------
__global__ __launch_bounds__(256) void perm_kernel(
    const int* __restrict__ src, const int* __restrict__ dst,
    int* __restrict__ cursor, int* __restrict__ gsrc) {
  const int e = blockIdx.x * 256 + threadIdx.x;
  if (e < EV) {
    const int pos = atomicAdd(&cursor[dst[e]], 1);
    gsrc[pos] = src[e];
  }
}

// ------- fused aggregate + combine, v3: 4 nodes/wave, W in VGPR -------
// Slot s = lane>>4 owns node n0+s with 16 lanes (q = lane&15, one float4
// of the 64-float row each). Gather: batches of 16 edges per slot, all
// 16 row-loads independent (masked FMA, no divergent guard). Combine:
// lane f holds Ws[:,f], Wd[:,f] in 128 VGPRs; s1/h rows broadcast from
// wave-private LDS (no barriers after weight staging; none at all here).
__global__ __launch_bounds__(256) void aggcomb_kernel(
    const float* __restrict__ hin, float* __restrict__ hout,
    const int* __restrict__ gsrc, const int* __restrict__ off,
    const float* __restrict__ wconv, const float* __restrict__ cb,
    const float* __restrict__ gamma, const float* __restrict__ beta,
    const float* __restrict__ mean, const float* __restrict__ var) {
  __shared__ float sS1[4][4][HD];   // wave x slot x row  (4 KB)
  __shared__ float sH[4][4][HD];    // wave x slot x own-h (4 KB)
  const int wave = threadIdx.x >> 6;
  const int lane = threadIdx.x & 63;
  const int sub = lane >> 4;   // node slot 0..3
  const int q = lane & 15;     // float4 slot within row
  const int f = lane;          // output feature in combine phase
  // weight columns into registers (static-index, fully unrolled)
  float Wsr[HD], Wdr[HD];
#pragma unroll
  for (int k = 0; k < HD; k++) Wsr[k] = wconv[k * HD + f];
#pragma unroll
  for (int k = 0; k < HD; k++) Wdr[k] = wconv[(HD + k) * HD + f];
  const float cbf = cb[f];
  const float gf = gamma[f];
  const float btf = beta[f];
  const float mf = mean[f];
  const float inv = rsqrtf(var[f] + 1e-3f);
  const float4* hp = (const float4*)hin;
  const int wid = blockIdx.x * 4 + wave;
  const int nw = gridDim.x * 4;
  const int ngroups = NV / 4;            // 12500 exactly
  for (int g = wid; g < ngroups; g += nw) {
    const int n0 = g * 4;
    const int n = n0 + sub;              // this slot's node
    const int j0 = off[n];
    const int deg = off[n + 1] - j0;
    int dm = deg;                        // wave-max degree
    dm = max(dm, __shfl_xor(dm, 16, 64));
    dm = max(dm, __shfl_xor(dm, 32, 64));
    const float4 hrow = hp[(size_t)n * 16 + q];   // own row fragment
    float4 acc = make_float4(0.f, 0.f, 0.f, 0.f);
    for (int base = 0; base < dm; base += 16) {
      const int e = base + q;
      const int eid = (e < deg) ? gsrc[j0 + e] : -1;
#pragma unroll
      for (int i = 0; i < 16; i++) {
        const int a = __shfl(eid, (sub << 4) | i, 64);
        const float4 v = hp[(size_t)max(a, 0) * 16 + q];
        const float msk = (a >= 0) ? 1.f : 0.f;
        acc.x = fmaf(v.x, msk, acc.x);
        acc.y = fmaf(v.y, msk, acc.y);
        acc.z = fmaf(v.z, msk, acc.z);
        acc.w = fmaf(v.w, msk, acc.w);
      }
    }
    // hand-off via wave-private LDS (in-order DS pipe; no barrier)
    ((float4*)sS1[wave][sub])[q] = acc;
    ((float4*)sH[wave][sub])[q] = hrow;
#pragma unroll
    for (int m4 = 0; m4 < 4; m4++) {
      const float4* s1p = (const float4*)sS1[wave][m4];
      const float4* hq = (const float4*)sH[wave][m4];
      float a1a = 0.f, a1b = 0.f, a2a = 0.f, a2b = 0.f;
#pragma unroll
      for (int k4 = 0; k4 < 16; k4++) {
        const float4 sv = s1p[k4];       // uniform addr -> broadcast
        const float4 hv = hq[k4];
        a1a = fmaf(sv.x, Wsr[4 * k4 + 0], a1a);
        a1b = fmaf(sv.y, Wsr[4 * k4 + 1], a1b);
        a1a = fmaf(sv.z, Wsr[4 * k4 + 2], a1a);
        a1b = fmaf(sv.w, Wsr[4 * k4 + 3], a1b);
        a2a = fmaf(hv.x, Wdr[4 * k4 + 0], a2a);
        a2b = fmaf(hv.y, Wdr[4 * k4 + 1], a2b);
        a2a = fmaf(hv.z, Wdr[4 * k4 + 2], a2a);
        a2b = fmaf(hv.w, Wdr[4 * k4 + 3], a2b);
      }
      const float a1 = a1a + a1b;
      const float a2 = a2a + a2b;
      const float hvf = sH[wave][m4][f];          // conflict-free b32
      const float d = (float)__shfl(deg, m4 << 4, 64);
      const float agg = a1 + d * a2 + d * cbf;
      const float sig = 1.f / (1.f + __expf(-agg));
      const float sp = fmaxf(hvf, 0.f) + log1pf(__expf(-fabsf(hvf)));
      float x = sig + sp;
      x = gf * (x - mf) * inv + btf;
      hout[(size_t)(n0 + m4) * HD + f] = fmaxf(x, 0.f);
    }
  }
}

// ------- convert h (fp32) -> hh (fp16, RNE) ---------------------------
__global__ __launch_bounds__(256) void convert_kernel(
    const float* __restrict__ h, __half* __restrict__ hh) {
  const int i = blockIdx.x * 256 + threadIdx.x;
  const int idx = i * 4;
  if (idx < NV * HD) {
    const float4 v = *(const float4*)(h + idx);
    __half2* o = (__half2*)(hh + idx);
    o[0] = __floats2half2_rn(v.x, v.y);
    o[1] = __floats2half2_rn(v.z, v.w);
  }
}

// ------- scores: 8 lanes/edge, fp16 rows (128 B each) -----------------
__global__ __launch_bounds__(256) void score_kernel(
    const __half* __restrict__ hh, const int* __restrict__ src,
    const int* __restrict__ dst, const int* __restrict__ neg_dst,
    const float* __restrict__ wrel, float* __restrict__ out) {
  const int tid = blockIdx.x * 256 + threadIdx.x;
  const int e = tid >> 3;
  const int q = tid & 7;
  if (e >= EV) return;
  const float4 w0 = ((const float4*)wrel)[2 * q];
  const float4 w1 = ((const float4*)wrel)[2 * q + 1];
  const int s = src[e];
  const int d = dst[e];
  int nd[KNEG];
#pragma unroll
  for (int r = 0; r < KNEG; r++) nd[r] = neg_dst[e * KNEG + r];

  const uint4* hp = (const uint4*)hh;
  const uint4 sv = hp[(size_t)s * 8 + q];
  const uint4 dv = hp[(size_t)d * 8 + q];
  uint4 nv[KNEG];
#pragma unroll
  for (int r = 0; r < KNEG; r++) nv[r] = hp[(size_t)nd[r] * 8 + q];

#define FLO(u) __half2float(__low2half(*(const __half2*)&(u)))
#define FHI(u) __half2float(__high2half(*(const __half2*)&(u)))
  const float a0 = FLO(sv.x) * w0.x, a1 = FHI(sv.x) * w0.y;
  const float a2 = FLO(sv.y) * w0.z, a3 = FHI(sv.y) * w0.w;
  const float a4 = FLO(sv.z) * w1.x, a5 = FHI(sv.z) * w1.y;
  const float a6 = FLO(sv.w) * w1.z, a7 = FHI(sv.w) * w1.w;

  float p = a0 * FLO(dv.x) + a1 * FHI(dv.x) + a2 * FLO(dv.y) + a3 * FHI(dv.y)
          + a4 * FLO(dv.z) + a5 * FHI(dv.z) + a6 * FLO(dv.w) + a7 * FHI(dv.w);
#pragma unroll
  for (int m = 4; m; m >>= 1) p += __shfl_xor(p, m, 64);
  if (q == 0) out[e] = p;

#pragma unroll
  for (int r = 0; r < KNEG; r++) {
    const uint4 v = nv[r];
    float pn = a0 * FLO(v.x) + a1 * FHI(v.x) + a2 * FLO(v.y) + a3 * FHI(v.y)
             + a4 * FLO(v.z) + a5 * FHI(v.z) + a6 * FLO(v.w) + a7 * FHI(v.w);
#pragma unroll
    for (int m = 4; m; m >>= 1) pn += __shfl_xor(pn, m, 64);
    if (q == 0) out[(size_t)EV + (size_t)e * KNEG + r] = pn;
  }
#undef FLO
#undef FHI
}

extern "C" void kernel_launch(void* const* d_in, const int* in_sizes, int n_in,
                              void* d_out, int out_size, void* d_ws, size_t ws_size,
                              hipStream_t stream) {
  const float* node_feat = (const float*)d_in[0];
  const float* emb_w     = (const float*)d_in[1];
  const float* emb_b     = (const float*)d_in[2];
  const float* conv_w    = (const float*)d_in[3];
  const float* conv_b    = (const float*)d_in[4];
  const float* bn_gamma  = (const float*)d_in[5];
  const float* bn_beta   = (const float*)d_in[6];
  const float* bn_mean   = (const float*)d_in[7];
  const float* bn_var    = (const float*)d_in[8];
  const float* w_rel     = (const float*)d_in[9];
  const int*   src       = (const int*)d_in[10];
  const int*   dst       = (const int*)d_in[11];
  const int*   neg_dst   = (const int*)d_in[12];
  float* out = (float*)d_out;

  float* h   = (float*)d_ws;
  float* h2  = h + (size_t)NV * HD;
  int*   off = (int*)(h2 + (size_t)NV * HD);
  int*   gsrc = off + (NV + 1);
  int*   bsum = gsrc + EV;
  int*   deg = (int*)h2;           // alias: h2[0 .. NV)
  int*   cursor = ((int*)h2) + NV; // alias: h2[NV .. 2NV)
  __half* hh = (__half*)h2;        // alias: 6.4 MB of h2

  hipMemsetAsync(deg, 0, (size_t)NV * sizeof(int), stream);
  embed_hist_kernel<<<512, 256, 0, stream>>>(node_feat, emb_w, emb_b, h,
                                             dst, deg);
  scan_part_kernel<<<NB, 1024, 0, stream>>>(deg, off, bsum);
  scan_fix_kernel<<<NB, 1024, 0, stream>>>(bsum, off, cursor);
  perm_kernel<<<(EV + 255) / 256, 256, 0, stream>>>(src, dst, cursor, gsrc);

  // layer 0: h -> h2 ; layer 1: h2 -> h  (ping-pong)
  aggcomb_kernel<<<512, 256, 0, stream>>>(
      h, h2, gsrc, off, conv_w, conv_b,
      bn_gamma, bn_beta, bn_mean, bn_var);
  aggcomb_kernel<<<512, 256, 0, stream>>>(
      h2, h, gsrc, off, conv_w + 2 * HD * HD, conv_b + HD,
      bn_gamma + HD, bn_beta + HD, bn_mean + HD, bn_var + HD);

  convert_kernel<<<NV * HD / 4 / 256, 256, 0, stream>>>(h, hh);
  score_kernel<<<((size_t)EV * 8 + 255) / 256, 256, 0, stream>>>(
      hh, src, dst, neg_dst, w_rel, out);
}